// Round 7
// baseline (315.475 us; speedup 1.0000x reference)
//
#include <hip/hip_runtime.h>
#include <cstdint>
#include <cstddef>

static constexpr int NN = 100000;
static constexpr int NE = 1600000;
static constexpr float NEG = 0.2f;
static constexpr int NBUCK = 49;                 // dst >> 11 (2048 nodes/bucket)
static constexpr int BCAP  = 36864;              // mean 32768 + ~22 sigma slack
static constexpr int NBLK1 = 512;
static constexpr int CHUNK1 = (NE + NBLK1 - 1) / NBLK1;  // 3125

typedef __attribute__((ext_vector_type(8))) short short8v;   // 8 bf16 (4 VGPRs)
typedef __attribute__((ext_vector_type(4))) float floatx4;   // 4 f32 acc

// ---------------------------------------------------------------------------
__device__ inline short8v cvt8(const float4 a, const float4 b)
{
  const float v[8] = {a.x, a.y, a.z, a.w, b.x, b.y, b.z, b.w};
  uint32_t q[8];
#pragma unroll
  for (int j = 0; j < 8; ++j) {
    uint32_t u = __float_as_uint(v[j]);
    u += 0x7fff + ((u >> 16) & 1);   // round-to-nearest-even
    q[j] = u >> 16;
  }
  union { uint32_t u[4]; short8v s; } r;
  r.u[0] = q[0] | (q[1] << 16);
  r.u[1] = q[2] | (q[3] << 16);
  r.u[2] = q[4] | (q[5] << 16);
  r.u[3] = q[6] | (q[7] << 16);
  return r.s;
}

__device__ inline uint32_t cvt1(float x)
{
  uint32_t u = __float_as_uint(x);
  u += 0x7fff + ((u >> 16) & 1);
  return u >> 16;
}

// ---------------------------------------------------------------------------
__global__ __launch_bounds__(256) void cvt_w_kernel(
    const float* __restrict__ Wsrc, const float* __restrict__ Wdst,
    ushort* __restrict__ wb)
{
  const int i = (blockIdx.x * 256 + threadIdx.x) * 8;
  if (i >= 32768) return;
  const float* src = (i < 16384) ? (Wsrc + i) : (Wdst + (i - 16384));
  float4 a = *(const float4*)(src);
  float4 b = *(const float4*)(src + 4);
  short8v s = cvt8(a, b);
  *(short8v*)(wb + i) = s;
}

// ---------------------------------------------------------------------------
// MFMA projection GEMM: A = feat (f32 -> bf16 in-flight), B = wb register-
// resident. Cols 0-127 -> src_fc (bf16), cols 128-255 -> out (f32, + bias).
// ---------------------------------------------------------------------------
__global__ __launch_bounds__(256) void gemm_kernel(
    const float* __restrict__ feat, const ushort* __restrict__ wb,
    const float* __restrict__ bdst,
    ushort* __restrict__ src_fc, float* __restrict__ out)
{
  const int lane = threadIdx.x & 63;
  const int w    = threadIdx.x >> 6;       // wave 0..3
  const int c0   = w * 64;
  const int colq = lane & 15;
  const int kgrp = lane >> 4;

  short8v bf[4][4];
#pragma unroll
  for (int nt = 0; nt < 4; ++nt)
#pragma unroll
    for (int kt = 0; kt < 4; ++kt)
      bf[nt][kt] = *(const short8v*)(wb + (size_t)(c0 + nt * 16 + colq) * 128
                                        + kt * 32 + kgrp * 8);

  float bias[4];
#pragma unroll
  for (int nt = 0; nt < 4; ++nt) {
    const int col = c0 + nt * 16 + colq;
    bias[nt] = (col >= 128) ? bdst[col - 128] : 0.0f;
  }
  const bool is_dst = (c0 >= 128);

  for (int mt = blockIdx.x; mt < NN / 16; mt += gridDim.x) {
    const int row0 = mt * 16;
    short8v af[4];
#pragma unroll
    for (int kt = 0; kt < 4; ++kt) {
      const float* ap = feat + (size_t)(row0 + colq) * 128 + kt * 32 + kgrp * 8;
      float4 a = *(const float4*)ap;
      float4 b = *(const float4*)(ap + 4);
      af[kt] = cvt8(a, b);
    }
    floatx4 acc[4] = {{0,0,0,0},{0,0,0,0},{0,0,0,0},{0,0,0,0}};
#pragma unroll
    for (int kt = 0; kt < 4; ++kt)
#pragma unroll
      for (int nt = 0; nt < 4; ++nt)
        acc[nt] = __builtin_amdgcn_mfma_f32_16x16x32_bf16(af[kt], bf[nt][kt],
                                                          acc[nt], 0, 0, 0);
    // C/D: col = lane&15, row = (lane>>4)*4 + reg
#pragma unroll
    for (int nt = 0; nt < 4; ++nt) {
      const int col = c0 + nt * 16 + colq;
#pragma unroll
      for (int j = 0; j < 4; ++j) {
        const int rr = row0 + kgrp * 4 + j;
        if (!is_dst) src_fc[(size_t)rr * 128 + col] = (ushort)cvt1(acc[nt][j]);
        else         out[(size_t)rr * 128 + (col - 128)] = acc[nt][j] + bias[nt];
      }
    }
  }
}

// ---------------------------------------------------------------------------
// Attention projections, wave-per-node: reads each feat row exactly once.
// ---------------------------------------------------------------------------
__global__ __launch_bounds__(256) void attn_kernel(
    const float* __restrict__ feat, const float* __restrict__ asrc,
    const float* __restrict__ adst, float2* __restrict__ attn_s,
    float2* __restrict__ attn_d)
{
  const int lane = threadIdx.x & 63;
  const int k0 = 2 * lane;
  const float a0x = asrc[k0],       a0y = asrc[k0 + 1];
  const float a1x = asrc[128 + k0], a1y = asrc[128 + k0 + 1];
  const float d0x = adst[k0],       d0y = adst[k0 + 1];
  const float d1x = adst[128 + k0], d1y = adst[128 + k0 + 1];

  const int gw = (int)((blockIdx.x * 256 + threadIdx.x) >> 6);
  const int nw = (int)((gridDim.x * 256) >> 6);
  for (int n = gw; n < NN; n += nw) {
    const float2 f = *(const float2*)(feat + (size_t)n * 128 + k0);
    float p0 = f.x * a0x + f.y * a0y;
    float p1 = f.x * a1x + f.y * a1y;
    float p2 = f.x * d0x + f.y * d0y;
    float p3 = f.x * d1x + f.y * d1y;
#pragma unroll
    for (int o = 32; o > 0; o >>= 1) {
      p0 += __shfl_xor(p0, o, 64);
      p1 += __shfl_xor(p1, o, 64);
      p2 += __shfl_xor(p2, o, 64);
      p3 += __shfl_xor(p3, o, 64);
    }
    if (lane == 0) {
      attn_s[n] = make_float2(p0, p1);
      attn_d[n] = make_float2(p2, p3);
    }
  }
}

// ---------------------------------------------------------------------------
// Pass 1: coarse-bucket append + fused per-node histogram.
// Record (u64): [src:17 | dloc:11 | w0bf16:16 | w1bf16:16].
// Appends per bucket are dense (LDS-aggregated reservation) -> streaming
// full-line writes; no random line churn.
// ---------------------------------------------------------------------------
__global__ __launch_bounds__(256) void bucket_kernel(
    const int* __restrict__ src, const int* __restrict__ dst,
    const float2* __restrict__ attn_s, const float2* __restrict__ attn_d,
    int* __restrict__ bucket_next, int* __restrict__ cnt,
    unsigned long long* __restrict__ tmp)
{
  __shared__ int lofs[NBUCK];
  const int t = threadIdx.x;
  if (t < NBUCK) lofs[t] = 0;
  __syncthreads();

  const int e0 = blockIdx.x * CHUNK1;
  const int e1 = min(e0 + CHUNK1, NE);
  for (int e = e0 + t; e < e1; e += 256)
    atomicAdd(&lofs[dst[e] >> 11], 1);
  __syncthreads();

  if (t < NBUCK) {
    const int c = lofs[t];
    const int base = atomicAdd(&bucket_next[t], c);
    lofs[t] = t * BCAP + base;
  }
  __syncthreads();

  for (int e = e0 + t; e < e1; e += 256) {
    const int d = dst[e];
    const int s = src[e];
    const float2 as = attn_s[s];
    const float2 ad = attn_d[d];
    float l0 = as.x + ad.x;
    float l1 = as.y + ad.y;
    l0 = (l0 > 0.0f) ? l0 : NEG * l0;
    l1 = (l1 > 0.0f) ? l1 : NEG * l1;
    const uint32_t wp = cvt1(__expf(l0)) | (cvt1(__expf(l1)) << 16);
    const int pos = atomicAdd(&lofs[d >> 11], 1);
    tmp[pos] = ((unsigned long long)(unsigned)s << 43)
             | ((unsigned long long)(unsigned)(d & 2047) << 32)
             | (unsigned long long)wp;
    atomicAdd(&cnt[d], 1);
  }
}

__global__ __launch_bounds__(1024) void scan_block_sums(
    const int* __restrict__ cnt, int* __restrict__ bsum)
{
  __shared__ int lds[1024];
  const int i = blockIdx.x * 1024 + threadIdx.x;
  lds[threadIdx.x] = (i < NN) ? cnt[i] : 0;
  __syncthreads();
  for (int o = 512; o > 0; o >>= 1) {
    if (threadIdx.x < o) lds[threadIdx.x] += lds[threadIdx.x + o];
    __syncthreads();
  }
  if (threadIdx.x == 0) bsum[blockIdx.x] = lds[0];
}

__global__ void scan_partials(int* __restrict__ bsum, int nb)
{
  __shared__ int lds[128];
  const int t = threadIdx.x;
  const int v = (t < nb) ? bsum[t] : 0;
  lds[t] = v;
  __syncthreads();
  int x = v;
  for (int o = 1; o < 128; o <<= 1) {
    const int y = (t >= o) ? lds[t - o] : 0;
    __syncthreads();
    x += y;
    lds[t] = x;
    __syncthreads();
  }
  if (t < nb) bsum[t] = x - v;  // exclusive
}

__global__ __launch_bounds__(1024) void scan_final(
    const int* __restrict__ cnt, const int* __restrict__ bsum,
    int* __restrict__ rs, int* __restrict__ next)
{
  __shared__ int lds[1024];
  const int t = threadIdx.x;
  const int i = blockIdx.x * 1024 + t;
  const int v = (i < NN) ? cnt[i] : 0;
  lds[t] = v;
  __syncthreads();
  int x = v;
  for (int o = 1; o < 1024; o <<= 1) {
    const int y = (t >= o) ? lds[t - o] : 0;
    __syncthreads();
    x += y;
    lds[t] = x;
    __syncthreads();
  }
  const int excl = x - v + bsum[blockIdx.x];
  if (i < NN) { rs[i] = excl; next[i] = excl; }
  if (i == NN - 1) rs[NN] = excl + v;
}

// ---------------------------------------------------------------------------
// Pass 2: bucket -> final CSR. All 8 sub-blocks of a bucket share
// blockIdx%8 (same XCD under round-robin dispatch), so the bucket's 256 KB
// CSR region stays resident in one L2 and lines flush once, full.
// Final record (uint2): {src_byte_off, w0bf16|w1bf16<<16}.
// ---------------------------------------------------------------------------
__global__ __launch_bounds__(256) void csr_kernel(
    const unsigned long long* __restrict__ tmp,
    const int* __restrict__ bucket_next,
    int* __restrict__ next, uint2* __restrict__ edges)
{
  const int p  = blockIdx.x & 7;
  const int tq = blockIdx.x >> 3;        // 0..55
  const int bq = tq >> 3;                // 0..6
  const int j  = tq & 7;                 // sub-block 0..7
  const int b  = p + 8 * bq;
  if (b >= NBUCK) return;
  const int ncnt = bucket_next[b];
  const int chunk = (ncnt + 7) >> 3;
  const int i0 = j * chunk;
  const int i1 = min(i0 + chunk, ncnt);
  const unsigned long long* base = tmp + (size_t)b * BCAP;
  for (int i = i0 + threadIdx.x; i < i1; i += 256) {
    const unsigned long long r = base[i];
    const int s = (int)(r >> 43);
    const int d = (b << 11) + (int)((r >> 32) & 2047);
    const uint32_t wp = (uint32_t)r;
    const int pos = atomicAdd(&next[d], 1);
    edges[pos] = make_uint2((unsigned)s * 256u, wp);
  }
}

// ---------------------------------------------------------------------------
// Aggregation: one wave per destination node; 8 B records (bf16 weights);
// 3-stage, 8-edge-wide pipeline.
// ---------------------------------------------------------------------------
__global__ __launch_bounds__(256) void aggregate_kernel(
    const int* __restrict__ rs, const uint2* __restrict__ edges,
    const ushort* __restrict__ src_fc, float* __restrict__ out)
{
  int wid = (int)((blockIdx.x * (size_t)blockDim.x + threadIdx.x) >> 6);
  if (wid >= NN) return;
  wid = __builtin_amdgcn_readfirstlane(wid);
  const int lane = threadIdx.x & 63;
  const int start = rs[wid];
  const int end = rs[wid + 1];
  const int deg = end - start;
  if (deg == 0) return;   // isolated node: out already = feat_dst_fc

  const bool h0 = (lane < 32);
  const unsigned lane4 = lane * 4;          // byte offset within bf16 row
  const char* fcb = (const char*)src_fc;
  const int nb = (deg + 7) >> 3;

  struct Batch { uint2 e[8]; };
  struct Rows  { uint32_t r[8]; };

  auto loadE = [&](int b, Batch& B) {
    const int base = start + b * 8;
#pragma unroll
    for (int j = 0; j < 8; ++j) {
      const int idx = (base + j < end) ? base + j : start;
      B.e[j] = edges[idx];                   // uniform -> scalar loads
    }
  };
  auto loadR = [&](const Batch& B, Rows& R) {
#pragma unroll
    for (int j = 0; j < 8; ++j)
      R.r[j] = *(const uint32_t*)(fcb + (B.e[j].x + lane4));
  };

  float acc0 = 0.0f, acc1 = 0.0f, dh = 0.0f;
  auto compute = [&](int b, const Batch& B, const Rows& R) {
    const int rem = deg - b * 8;
#pragma unroll
    for (int j = 0; j < 8; ++j) {
      const uint32_t wp = (j < rem) ? B.e[j].y : 0u;   // scalar select
      const float w0 = __uint_as_float(wp << 16);
      const float w1 = __uint_as_float(wp & 0xffff0000u);
      const float wh = h0 ? w0 : w1;
      dh += wh;
      acc0 = fmaf(__uint_as_float(R.r[j] << 16), wh, acc0);
      acc1 = fmaf(__uint_as_float(R.r[j] & 0xffff0000u), wh, acc1);
    }
  };

  Batch bA, bB;
  Rows rA;
  loadE(0, bA);
  loadR(bA, rA);
  if (nb > 1) loadE(1, bB); else bB = bA;

  for (int b = 0; b < nb; ++b) {
    Rows rB = rA;
    if (b + 1 < nb) loadR(bB, rB);
    Batch bC = bB;
    if (b + 2 < nb) loadE(b + 2, bC);
    compute(b, bA, rA);
    bA = bB; rA = rB; bB = bC;
  }

  const float inv = 1.0f / dh;
  float2* po = (float2*)(out + (size_t)wid * 128 + 2 * lane);
  float2 cur = *po;
  cur.x = fmaf(acc0, inv, cur.x);
  cur.y = fmaf(acc1, inv, cur.y);
  *po = cur;
}

// ---------------------------------------------------------------------------
extern "C" void kernel_launch(void* const* d_in, const int* in_sizes, int n_in,
                              void* d_out, int out_size, void* d_ws, size_t ws_size,
                              hipStream_t stream)
{
  const float* feat    = (const float*)d_in[0];
  const int*   src_idx = (const int*)d_in[1];
  const int*   dst_idx = (const int*)d_in[2];
  const float* Wsrc    = (const float*)d_in[3];
  const float* Wdst    = (const float*)d_in[4];
  const float* bdst    = (const float*)d_in[5];
  const float* asrc    = (const float*)d_in[6];
  const float* adst    = (const float*)d_in[7];
  float* out = (float*)d_out;

  char* ws = (char*)d_ws;
  size_t off = 0;
  auto alloc = [&](size_t bytes) -> void* {
    void* p = ws + off;
    off = (off + bytes + 255) & ~(size_t)255;
    return p;
  };
  ushort* src_fc  = (ushort*)alloc((size_t)NN * 128 * sizeof(ushort));   // 25.6 MB
  float*  attn_s  = (float*)alloc((size_t)NN * 2 * sizeof(float));
  float*  attn_d  = (float*)alloc((size_t)NN * 2 * sizeof(float));
  int*    cnt     = (int*)alloc((size_t)NN * sizeof(int));
  int*    rs      = (int*)alloc((size_t)(NN + 1) * sizeof(int));
  int*    next    = (int*)alloc((size_t)NN * sizeof(int));
  uint2*  edges   = (uint2*)alloc((size_t)NE * sizeof(uint2));           // 12.8 MB
  unsigned long long* tmp =
      (unsigned long long*)alloc((size_t)NBUCK * BCAP * sizeof(unsigned long long)); // 14.5 MB
  int*    bnext   = (int*)alloc((size_t)NBUCK * sizeof(int));
  int*    bsum    = (int*)alloc(128 * sizeof(int));
  ushort* wb      = (ushort*)alloc((size_t)256 * 128 * sizeof(ushort));

  hipMemsetAsync(cnt, 0, (size_t)NN * sizeof(int), stream);
  hipMemsetAsync(bnext, 0, (size_t)NBUCK * sizeof(int), stream);

  cvt_w_kernel<<<16, 256, 0, stream>>>(Wsrc, Wdst, wb);
  gemm_kernel<<<2048, 256, 0, stream>>>(feat, wb, bdst, src_fc, out);
  attn_kernel<<<1024, 256, 0, stream>>>(feat, asrc, adst,
                                        (float2*)attn_s, (float2*)attn_d);
  bucket_kernel<<<NBLK1, 256, 0, stream>>>(
      src_idx, dst_idx, (const float2*)attn_s, (const float2*)attn_d,
      bnext, cnt, tmp);

  constexpr int NB = (NN + 1023) / 1024;  // 98
  scan_block_sums<<<NB, 1024, 0, stream>>>(cnt, bsum);
  scan_partials<<<1, 128, 0, stream>>>(bsum, NB);
  scan_final<<<NB, 1024, 0, stream>>>(cnt, bsum, rs, next);

  csr_kernel<<<448, 256, 0, stream>>>(tmp, bnext, next, edges);
  aggregate_kernel<<<(NN * 64) / 256, 256, 0, stream>>>(rs, edges, src_fc, out);
}

// Round 8
// 263.023 us; speedup vs baseline: 1.1994x; 1.1994x over previous
//
#include <hip/hip_runtime.h>
#include <cstdint>
#include <cstddef>

static constexpr int NN = 100000;
static constexpr int NE = 1600000;
static constexpr float NEG = 0.2f;
static constexpr int NBUCK = 49;                 // dst >> 11 (2048 nodes/bucket)
static constexpr int BCAP  = 36864;              // mean 32768 + ~22 sigma slack
static constexpr int NBLK1 = 512;
static constexpr int CHUNK1 = (NE + NBLK1 - 1) / NBLK1;  // 3125

typedef __attribute__((ext_vector_type(8))) short short8v;   // 8 bf16 (4 VGPRs)
typedef __attribute__((ext_vector_type(4))) float floatx4;   // 4 f32 acc

// ---------------------------------------------------------------------------
__device__ inline short8v cvt8(const float4 a, const float4 b)
{
  const float v[8] = {a.x, a.y, a.z, a.w, b.x, b.y, b.z, b.w};
  uint32_t q[8];
#pragma unroll
  for (int j = 0; j < 8; ++j) {
    uint32_t u = __float_as_uint(v[j]);
    u += 0x7fff + ((u >> 16) & 1);   // round-to-nearest-even
    q[j] = u >> 16;
  }
  union { uint32_t u[4]; short8v s; } r;
  r.u[0] = q[0] | (q[1] << 16);
  r.u[1] = q[2] | (q[3] << 16);
  r.u[2] = q[4] | (q[5] << 16);
  r.u[3] = q[6] | (q[7] << 16);
  return r.s;
}

__device__ inline uint32_t cvt1(float x)
{
  uint32_t u = __float_as_uint(x);
  u += 0x7fff + ((u >> 16) & 1);
  return u >> 16;
}

// ---------------------------------------------------------------------------
__global__ __launch_bounds__(256) void cvt_w_kernel(
    const float* __restrict__ Wsrc, const float* __restrict__ Wdst,
    ushort* __restrict__ wb)
{
  const int i = (blockIdx.x * 256 + threadIdx.x) * 8;
  if (i >= 32768) return;
  const float* src = (i < 16384) ? (Wsrc + i) : (Wdst + (i - 16384));
  float4 a = *(const float4*)(src);
  float4 b = *(const float4*)(src + 4);
  short8v s = cvt8(a, b);
  *(short8v*)(wb + i) = s;
}

// ---------------------------------------------------------------------------
// MFMA projection GEMM: A = feat (f32 -> bf16 in-flight), B = wb register-
// resident. Cols 0-127 -> src_fc (bf16), cols 128-255 -> out (f32, + bias).
// ---------------------------------------------------------------------------
__global__ __launch_bounds__(256) void gemm_kernel(
    const float* __restrict__ feat, const ushort* __restrict__ wb,
    const float* __restrict__ bdst,
    ushort* __restrict__ src_fc, float* __restrict__ out)
{
  const int lane = threadIdx.x & 63;
  const int w    = threadIdx.x >> 6;       // wave 0..3
  const int c0   = w * 64;
  const int colq = lane & 15;
  const int kgrp = lane >> 4;

  short8v bf[4][4];
#pragma unroll
  for (int nt = 0; nt < 4; ++nt)
#pragma unroll
    for (int kt = 0; kt < 4; ++kt)
      bf[nt][kt] = *(const short8v*)(wb + (size_t)(c0 + nt * 16 + colq) * 128
                                        + kt * 32 + kgrp * 8);

  float bias[4];
#pragma unroll
  for (int nt = 0; nt < 4; ++nt) {
    const int col = c0 + nt * 16 + colq;
    bias[nt] = (col >= 128) ? bdst[col - 128] : 0.0f;
  }
  const bool is_dst = (c0 >= 128);

  for (int mt = blockIdx.x; mt < NN / 16; mt += gridDim.x) {
    const int row0 = mt * 16;
    short8v af[4];
#pragma unroll
    for (int kt = 0; kt < 4; ++kt) {
      const float* ap = feat + (size_t)(row0 + colq) * 128 + kt * 32 + kgrp * 8;
      float4 a = *(const float4*)ap;
      float4 b = *(const float4*)(ap + 4);
      af[kt] = cvt8(a, b);
    }
    floatx4 acc[4] = {{0,0,0,0},{0,0,0,0},{0,0,0,0},{0,0,0,0}};
#pragma unroll
    for (int kt = 0; kt < 4; ++kt)
#pragma unroll
      for (int nt = 0; nt < 4; ++nt)
        acc[nt] = __builtin_amdgcn_mfma_f32_16x16x32_bf16(af[kt], bf[nt][kt],
                                                          acc[nt], 0, 0, 0);
    // C/D: col = lane&15, row = (lane>>4)*4 + reg
#pragma unroll
    for (int nt = 0; nt < 4; ++nt) {
      const int col = c0 + nt * 16 + colq;
#pragma unroll
      for (int j = 0; j < 4; ++j) {
        const int rr = row0 + kgrp * 4 + j;
        if (!is_dst) src_fc[(size_t)rr * 128 + col] = (ushort)cvt1(acc[nt][j]);
        else         out[(size_t)rr * 128 + (col - 128)] = acc[nt][j] + bias[nt];
      }
    }
  }
}

// ---------------------------------------------------------------------------
// Attention projections, wave-per-node: reads each feat row exactly once.
// ---------------------------------------------------------------------------
__global__ __launch_bounds__(256) void attn_kernel(
    const float* __restrict__ feat, const float* __restrict__ asrc,
    const float* __restrict__ adst, float2* __restrict__ attn_s,
    float2* __restrict__ attn_d)
{
  const int lane = threadIdx.x & 63;
  const int k0 = 2 * lane;
  const float a0x = asrc[k0],       a0y = asrc[k0 + 1];
  const float a1x = asrc[128 + k0], a1y = asrc[128 + k0 + 1];
  const float d0x = adst[k0],       d0y = adst[k0 + 1];
  const float d1x = adst[128 + k0], d1y = adst[128 + k0 + 1];

  const int gw = (int)((blockIdx.x * 256 + threadIdx.x) >> 6);
  const int nw = (int)((gridDim.x * 256) >> 6);
  for (int n = gw; n < NN; n += nw) {
    const float2 f = *(const float2*)(feat + (size_t)n * 128 + k0);
    float p0 = f.x * a0x + f.y * a0y;
    float p1 = f.x * a1x + f.y * a1y;
    float p2 = f.x * d0x + f.y * d0y;
    float p3 = f.x * d1x + f.y * d1y;
#pragma unroll
    for (int o = 32; o > 0; o >>= 1) {
      p0 += __shfl_xor(p0, o, 64);
      p1 += __shfl_xor(p1, o, 64);
      p2 += __shfl_xor(p2, o, 64);
      p3 += __shfl_xor(p3, o, 64);
    }
    if (lane == 0) {
      attn_s[n] = make_float2(p0, p1);
      attn_d[n] = make_float2(p2, p3);
    }
  }
}

// ---------------------------------------------------------------------------
// Pass 1: coarse-bucket append. Record (u64):
// [src:17 | dloc:11 | w0bf16:16 | w1bf16:16]. Per-block two-pass: LDS bucket
// count -> one global reservation per bucket -> dense append (streaming
// writes). NO per-node histogram atomics (rs derived later from records).
// ---------------------------------------------------------------------------
__global__ __launch_bounds__(1024) void bucket_kernel(
    const int* __restrict__ src, const int* __restrict__ dst,
    const float2* __restrict__ attn_s, const float2* __restrict__ attn_d,
    int* __restrict__ bucket_next, unsigned long long* __restrict__ tmp)
{
  __shared__ int lofs[NBUCK];
  const int t = threadIdx.x;
  if (t < NBUCK) lofs[t] = 0;
  __syncthreads();

  const int e0 = blockIdx.x * CHUNK1;
  const int e1 = min(e0 + CHUNK1, NE);
  for (int e = e0 + t; e < e1; e += 1024)
    atomicAdd(&lofs[dst[e] >> 11], 1);
  __syncthreads();

  if (t < NBUCK) {
    const int c = lofs[t];
    const int base = atomicAdd(&bucket_next[t], c);
    lofs[t] = t * BCAP + base;
  }
  __syncthreads();

  for (int e = e0 + t; e < e1; e += 1024) {
    const int d = dst[e];
    const int s = src[e];
    const float2 as = attn_s[s];
    const float2 ad = attn_d[d];
    float l0 = as.x + ad.x;
    float l1 = as.y + ad.y;
    l0 = (l0 > 0.0f) ? l0 : NEG * l0;
    l1 = (l1 > 0.0f) ? l1 : NEG * l1;
    const uint32_t wp = cvt1(__expf(l0)) | (cvt1(__expf(l1)) << 16);
    const int pos = atomicAdd(&lofs[d >> 11], 1);
    tmp[pos] = ((unsigned long long)(unsigned)s << 43)
             | ((unsigned long long)(unsigned)(d & 2047) << 32)
             | (unsigned long long)wp;
  }
}

// ---------------------------------------------------------------------------
// rs build: one block per bucket. LDS-histogram the 11-bit local dst over the
// bucket's records, block-scan (pair + Hillis-Steele over 1024 pair-sums),
// write rs/next for the bucket's contiguous node range (coalesced).
// Replaces the per-node atomic histogram + 3-kernel global scan.
// ---------------------------------------------------------------------------
__global__ __launch_bounds__(1024) void rs_build_kernel(
    const unsigned long long* __restrict__ tmp,
    const int* __restrict__ bucket_next,
    int* __restrict__ rs, int* __restrict__ next)
{
  __shared__ int hist[2048];
  __shared__ int ps[1024];
  __shared__ int bstart_s;
  const int b = blockIdx.x;
  const int t = threadIdx.x;
  hist[t] = 0;
  hist[t + 1024] = 0;
  if (t == 0) {
    int ssum = 0;
    for (int k = 0; k < b; ++k) ssum += bucket_next[k];
    bstart_s = ssum;
  }
  __syncthreads();

  const int ncnt = bucket_next[b];
  const unsigned long long* base = tmp + (size_t)b * BCAP;
  for (int i = t; i < ncnt; i += 1024)
    atomicAdd(&hist[(int)((base[i] >> 32) & 2047)], 1);
  __syncthreads();

  const int h0 = hist[2 * t];
  const int h1 = hist[2 * t + 1];
  const int pv = h0 + h1;
  ps[t] = pv;
  __syncthreads();
  int x = pv;
  for (int o = 1; o < 1024; o <<= 1) {
    const int y = (t >= o) ? ps[t - o] : 0;
    __syncthreads();
    x += y;
    ps[t] = x;
    __syncthreads();
  }
  const int e0 = bstart_s + x - pv;          // exclusive prefix at node 2t
  const int n0 = b * 2048 + 2 * t;
  if (n0 < NN)     { rs[n0] = e0;          next[n0] = e0; }
  if (n0 + 1 < NN) { rs[n0 + 1] = e0 + h0; next[n0 + 1] = e0 + h0; }
  if (b == NBUCK - 1 && t == 0) rs[NN] = NE;
}

// ---------------------------------------------------------------------------
// Pass 2: bucket -> final CSR. All 8 sub-blocks of a bucket share
// blockIdx%8 (same XCD under round-robin dispatch); the bucket's ~256 KB
// CSR region stays in one L2, lines flush once, full.
// ---------------------------------------------------------------------------
__global__ __launch_bounds__(256) void csr_kernel(
    const unsigned long long* __restrict__ tmp,
    const int* __restrict__ bucket_next,
    int* __restrict__ next, uint2* __restrict__ edges)
{
  const int p  = blockIdx.x & 7;
  const int tq = blockIdx.x >> 3;        // 0..55
  const int bq = tq >> 3;                // 0..6
  const int j  = tq & 7;                 // sub-block 0..7
  const int b  = p + 8 * bq;
  if (b >= NBUCK) return;
  const int ncnt = bucket_next[b];
  const int chunk = (ncnt + 7) >> 3;
  const int i0 = j * chunk;
  const int i1 = min(i0 + chunk, ncnt);
  const unsigned long long* base = tmp + (size_t)b * BCAP;
  for (int i = i0 + threadIdx.x; i < i1; i += 256) {
    const unsigned long long r = base[i];
    const int s = (int)(r >> 43);
    const int d = (b << 11) + (int)((r >> 32) & 2047);
    const uint32_t wp = (uint32_t)r;
    const int pos = atomicAdd(&next[d], 1);
    edges[pos] = make_uint2((unsigned)s * 256u, wp);
  }
}

// ---------------------------------------------------------------------------
// Aggregation: one wave per destination node; 8 B records (bf16 weights);
// 3-stage, 8-edge-wide pipeline.
// ---------------------------------------------------------------------------
__global__ __launch_bounds__(256) void aggregate_kernel(
    const int* __restrict__ rs, const uint2* __restrict__ edges,
    const ushort* __restrict__ src_fc, float* __restrict__ out)
{
  int wid = (int)((blockIdx.x * (size_t)blockDim.x + threadIdx.x) >> 6);
  if (wid >= NN) return;
  wid = __builtin_amdgcn_readfirstlane(wid);
  const int lane = threadIdx.x & 63;
  const int start = rs[wid];
  const int end = rs[wid + 1];
  const int deg = end - start;
  if (deg == 0) return;   // isolated node: out already = feat_dst_fc

  const bool h0 = (lane < 32);
  const unsigned lane4 = lane * 4;          // byte offset within bf16 row
  const char* fcb = (const char*)src_fc;
  const int nb = (deg + 7) >> 3;

  struct Batch { uint2 e[8]; };
  struct Rows  { uint32_t r[8]; };

  auto loadE = [&](int b, Batch& B) {
    const int base = start + b * 8;
#pragma unroll
    for (int j = 0; j < 8; ++j) {
      const int idx = (base + j < end) ? base + j : start;
      B.e[j] = edges[idx];                   // uniform -> scalar loads
    }
  };
  auto loadR = [&](const Batch& B, Rows& R) {
#pragma unroll
    for (int j = 0; j < 8; ++j)
      R.r[j] = *(const uint32_t*)(fcb + (B.e[j].x + lane4));
  };

  float acc0 = 0.0f, acc1 = 0.0f, dh = 0.0f;
  auto compute = [&](int b, const Batch& B, const Rows& R) {
    const int rem = deg - b * 8;
#pragma unroll
    for (int j = 0; j < 8; ++j) {
      const uint32_t wp = (j < rem) ? B.e[j].y : 0u;   // scalar select
      const float w0 = __uint_as_float(wp << 16);
      const float w1 = __uint_as_float(wp & 0xffff0000u);
      const float wh = h0 ? w0 : w1;
      dh += wh;
      acc0 = fmaf(__uint_as_float(R.r[j] << 16), wh, acc0);
      acc1 = fmaf(__uint_as_float(R.r[j] & 0xffff0000u), wh, acc1);
    }
  };

  Batch bA, bB;
  Rows rA;
  loadE(0, bA);
  loadR(bA, rA);
  if (nb > 1) loadE(1, bB); else bB = bA;

  for (int b = 0; b < nb; ++b) {
    Rows rB = rA;
    if (b + 1 < nb) loadR(bB, rB);
    Batch bC = bB;
    if (b + 2 < nb) loadE(b + 2, bC);
    compute(b, bA, rA);
    bA = bB; rA = rB; bB = bC;
  }

  const float inv = 1.0f / dh;
  float2* po = (float2*)(out + (size_t)wid * 128 + 2 * lane);
  float2 cur = *po;
  cur.x = fmaf(acc0, inv, cur.x);
  cur.y = fmaf(acc1, inv, cur.y);
  *po = cur;
}

// ---------------------------------------------------------------------------
extern "C" void kernel_launch(void* const* d_in, const int* in_sizes, int n_in,
                              void* d_out, int out_size, void* d_ws, size_t ws_size,
                              hipStream_t stream)
{
  const float* feat    = (const float*)d_in[0];
  const int*   src_idx = (const int*)d_in[1];
  const int*   dst_idx = (const int*)d_in[2];
  const float* Wsrc    = (const float*)d_in[3];
  const float* Wdst    = (const float*)d_in[4];
  const float* bdst    = (const float*)d_in[5];
  const float* asrc    = (const float*)d_in[6];
  const float* adst    = (const float*)d_in[7];
  float* out = (float*)d_out;

  char* ws = (char*)d_ws;
  size_t off = 0;
  auto alloc = [&](size_t bytes) -> void* {
    void* p = ws + off;
    off = (off + bytes + 255) & ~(size_t)255;
    return p;
  };
  ushort* src_fc  = (ushort*)alloc((size_t)NN * 128 * sizeof(ushort));   // 25.6 MB
  float*  attn_s  = (float*)alloc((size_t)NN * 2 * sizeof(float));
  float*  attn_d  = (float*)alloc((size_t)NN * 2 * sizeof(float));
  int*    rs      = (int*)alloc((size_t)(NN + 1) * sizeof(int));
  int*    next    = (int*)alloc((size_t)NN * sizeof(int));
  uint2*  edges   = (uint2*)alloc((size_t)NE * sizeof(uint2));           // 12.8 MB
  unsigned long long* tmp =
      (unsigned long long*)alloc((size_t)NBUCK * BCAP * sizeof(unsigned long long)); // 14.5 MB
  int*    bnext   = (int*)alloc((size_t)NBUCK * sizeof(int));
  ushort* wb      = (ushort*)alloc((size_t)256 * 128 * sizeof(ushort));

  hipMemsetAsync(bnext, 0, (size_t)NBUCK * sizeof(int), stream);

  cvt_w_kernel<<<16, 256, 0, stream>>>(Wsrc, Wdst, wb);
  gemm_kernel<<<2048, 256, 0, stream>>>(feat, wb, bdst, src_fc, out);
  attn_kernel<<<1024, 256, 0, stream>>>(feat, asrc, adst,
                                        (float2*)attn_s, (float2*)attn_d);
  bucket_kernel<<<NBLK1, 1024, 0, stream>>>(
      src_idx, dst_idx, (const float2*)attn_s, (const float2*)attn_d,
      bnext, tmp);
  rs_build_kernel<<<NBUCK, 1024, 0, stream>>>(tmp, bnext, rs, next);
  csr_kernel<<<448, 256, 0, stream>>>(tmp, bnext, next, edges);
  aggregate_kernel<<<(NN * 64) / 256, 256, 0, stream>>>(rs, edges, src_fc, out);
}

// Round 9
// 223.713 us; speedup vs baseline: 1.4102x; 1.1757x over previous
//
#include <hip/hip_runtime.h>
#include <cstdint>
#include <cstddef>

static constexpr int NN = 100000;
static constexpr int NE = 1600000;
static constexpr float NEG = 0.2f;
static constexpr int NBUCK = 49;                 // dst >> 11 (2048 nodes/bucket)
static constexpr int BCAP  = 36864;              // mean 32768 + ~22 sigma slack
static constexpr int NBLK1 = 512;
static constexpr int CHUNK1 = (NE + NBLK1 - 1) / NBLK1;  // 3125

typedef __attribute__((ext_vector_type(8))) short short8v;   // 8 bf16 (4 VGPRs)
typedef __attribute__((ext_vector_type(4))) float floatx4;   // 4 f32 acc

// ---------------------------------------------------------------------------
__device__ inline short8v cvt8(const float4 a, const float4 b)
{
  const float v[8] = {a.x, a.y, a.z, a.w, b.x, b.y, b.z, b.w};
  uint32_t q[8];
#pragma unroll
  for (int j = 0; j < 8; ++j) {
    uint32_t u = __float_as_uint(v[j]);
    u += 0x7fff + ((u >> 16) & 1);   // round-to-nearest-even
    q[j] = u >> 16;
  }
  union { uint32_t u[4]; short8v s; } r;
  r.u[0] = q[0] | (q[1] << 16);
  r.u[1] = q[2] | (q[3] << 16);
  r.u[2] = q[4] | (q[5] << 16);
  r.u[3] = q[6] | (q[7] << 16);
  return r.s;
}

__device__ inline uint32_t cvt1(float x)
{
  uint32_t u = __float_as_uint(x);
  u += 0x7fff + ((u >> 16) & 1);
  return u >> 16;
}

// ---------------------------------------------------------------------------
__global__ __launch_bounds__(256) void cvt_w_kernel(
    const float* __restrict__ Wsrc, const float* __restrict__ Wdst,
    ushort* __restrict__ wb)
{
  const int i = (blockIdx.x * 256 + threadIdx.x) * 8;
  if (i >= 32768) return;
  const float* src = (i < 16384) ? (Wsrc + i) : (Wdst + (i - 16384));
  float4 a = *(const float4*)(src);
  float4 b = *(const float4*)(src + 4);
  short8v s = cvt8(a, b);
  *(short8v*)(wb + i) = s;
}

// ---------------------------------------------------------------------------
// MFMA projection GEMM with LDS-staged A: 256 threads load+convert the
// 16x128 f32 A-tile to bf16 LDS ONCE per block (was 4x duplicated per wave).
// XOR swizzle (byte ^= (row&7)<<4) keeps fragment ds_read_b128 conflict-free.
// B register-resident per wave (64 cols). Cols 0-127 -> src_fc (bf16),
// cols 128-255 -> out (f32, + bias).
// ---------------------------------------------------------------------------
__global__ __launch_bounds__(256) void gemm_kernel(
    const float* __restrict__ feat, const ushort* __restrict__ wb,
    const float* __restrict__ bdst,
    ushort* __restrict__ src_fc, float* __restrict__ out)
{
  __shared__ __align__(16) ushort atile[2048];   // 16 x 128 bf16, swizzled

  const int t    = threadIdx.x;
  const int lane = t & 63;
  const int w    = t >> 6;                 // wave 0..3
  const int c0   = w * 64;
  const int colq = lane & 15;
  const int kgrp = lane >> 4;

  short8v bf[4][4];
#pragma unroll
  for (int nt = 0; nt < 4; ++nt)
#pragma unroll
    for (int kt = 0; kt < 4; ++kt)
      bf[nt][kt] = *(const short8v*)(wb + (size_t)(c0 + nt * 16 + colq) * 128
                                        + kt * 32 + kgrp * 8);

  float bias[4];
#pragma unroll
  for (int nt = 0; nt < 4; ++nt) {
    const int col = c0 + nt * 16 + colq;
    bias[nt] = (col >= 128) ? bdst[col - 128] : 0.0f;
  }
  const bool is_dst = (c0 >= 128);

  const int sr = t >> 4;                   // staging row 0..15
  const int sc = t & 15;                   // staging col-group (8 floats)
  const unsigned sw_off = (unsigned)((sr * 256 + sc * 16) ^ ((sr & 7) << 4));
  unsigned rd_off[4];
#pragma unroll
  for (int kt = 0; kt < 4; ++kt)
    rd_off[kt] = (unsigned)((colq * 256 + kt * 64 + kgrp * 16) ^ ((colq & 7) << 4));

  for (int mt = blockIdx.x; mt < NN / 16; mt += gridDim.x) {
    const int row0 = mt * 16;
    // stage A-tile: each thread converts 8 floats -> 8 bf16 in LDS
    {
      const float* ap = feat + (size_t)(row0 + sr) * 128 + sc * 8;
      float4 a = *(const float4*)ap;
      float4 b = *(const float4*)(ap + 4);
      *(short8v*)((char*)atile + sw_off) = cvt8(a, b);
    }
    __syncthreads();
    short8v af[4];
#pragma unroll
    for (int kt = 0; kt < 4; ++kt)
      af[kt] = *(const short8v*)((const char*)atile + rd_off[kt]);
    __syncthreads();   // reads drained before next iter's writes

    floatx4 acc[4] = {{0,0,0,0},{0,0,0,0},{0,0,0,0},{0,0,0,0}};
#pragma unroll
    for (int kt = 0; kt < 4; ++kt)
#pragma unroll
      for (int nt = 0; nt < 4; ++nt)
        acc[nt] = __builtin_amdgcn_mfma_f32_16x16x32_bf16(af[kt], bf[nt][kt],
                                                          acc[nt], 0, 0, 0);
    // C/D: col = lane&15, row = (lane>>4)*4 + reg
#pragma unroll
    for (int nt = 0; nt < 4; ++nt) {
      const int col = c0 + nt * 16 + colq;
#pragma unroll
      for (int j = 0; j < 4; ++j) {
        const int rr = row0 + kgrp * 4 + j;
        if (!is_dst) src_fc[(size_t)rr * 128 + col] = (ushort)cvt1(acc[nt][j]);
        else         out[(size_t)rr * 128 + (col - 128)] = acc[nt][j] + bias[nt];
      }
    }
  }
}

// ---------------------------------------------------------------------------
// Attention projections: 4 nodes per wave (16 lanes/node, 8 features/lane).
// Each lane preloads its 4x8 a-vector slice (loop-invariant); 4-step
// 16-lane shuffle reduce (vs 6-step 64-lane before).
// ---------------------------------------------------------------------------
__global__ __launch_bounds__(256) void attn_kernel(
    const float* __restrict__ feat, const float* __restrict__ asrc,
    const float* __restrict__ adst, float2* __restrict__ attn_s,
    float2* __restrict__ attn_d)
{
  const int lane = threadIdx.x & 63;
  const int sub = lane >> 4;               // node within wave's group of 4
  const int kl  = lane & 15;
  const int k0  = kl * 8;

  float4 a0a = *(const float4*)(asrc + k0),       a0b = *(const float4*)(asrc + k0 + 4);
  float4 a1a = *(const float4*)(asrc + 128 + k0), a1b = *(const float4*)(asrc + 128 + k0 + 4);
  float4 d0a = *(const float4*)(adst + k0),       d0b = *(const float4*)(adst + k0 + 4);
  float4 d1a = *(const float4*)(adst + 128 + k0), d1b = *(const float4*)(adst + 128 + k0 + 4);

  const int gw = (int)((blockIdx.x * 256 + threadIdx.x) >> 6);
  const int nw = (int)((gridDim.x * 256) >> 6);
  for (int base = gw * 4; base < NN; base += nw * 4) {
    const int n = base + sub;              // NN % 4 == 0 -> always < NN
    const float* fp = feat + (size_t)n * 128 + k0;
    const float4 f0 = *(const float4*)fp;
    const float4 f1 = *(const float4*)(fp + 4);
    float p0 = f0.x*a0a.x + f0.y*a0a.y + f0.z*a0a.z + f0.w*a0a.w
             + f1.x*a0b.x + f1.y*a0b.y + f1.z*a0b.z + f1.w*a0b.w;
    float p1 = f0.x*a1a.x + f0.y*a1a.y + f0.z*a1a.z + f0.w*a1a.w
             + f1.x*a1b.x + f1.y*a1b.y + f1.z*a1b.z + f1.w*a1b.w;
    float p2 = f0.x*d0a.x + f0.y*d0a.y + f0.z*d0a.z + f0.w*d0a.w
             + f1.x*d0b.x + f1.y*d0b.y + f1.z*d0b.z + f1.w*d0b.w;
    float p3 = f0.x*d1a.x + f0.y*d1a.y + f0.z*d1a.z + f0.w*d1a.w
             + f1.x*d1b.x + f1.y*d1b.y + f1.z*d1b.z + f1.w*d1b.w;
#pragma unroll
    for (int o = 8; o > 0; o >>= 1) {      // reduce within 16-lane group
      p0 += __shfl_xor(p0, o, 64);
      p1 += __shfl_xor(p1, o, 64);
      p2 += __shfl_xor(p2, o, 64);
      p3 += __shfl_xor(p3, o, 64);
    }
    if (kl == 0) {
      attn_s[n] = make_float2(p0, p1);
      attn_d[n] = make_float2(p2, p3);
    }
  }
}

// ---------------------------------------------------------------------------
// Pass 1: coarse-bucket append. Record (u64):
// [src:17 | dloc:11 | w0bf16:16 | w1bf16:16]. Per-block two-pass: LDS bucket
// count -> one global reservation per bucket -> dense append (streaming
// writes). NO per-node histogram atomics (rs derived later from records).
// ---------------------------------------------------------------------------
__global__ __launch_bounds__(1024) void bucket_kernel(
    const int* __restrict__ src, const int* __restrict__ dst,
    const float2* __restrict__ attn_s, const float2* __restrict__ attn_d,
    int* __restrict__ bucket_next, unsigned long long* __restrict__ tmp)
{
  __shared__ int lofs[NBUCK];
  const int t = threadIdx.x;
  if (t < NBUCK) lofs[t] = 0;
  __syncthreads();

  const int e0 = blockIdx.x * CHUNK1;
  const int e1 = min(e0 + CHUNK1, NE);
  for (int e = e0 + t; e < e1; e += 1024)
    atomicAdd(&lofs[dst[e] >> 11], 1);
  __syncthreads();

  if (t < NBUCK) {
    const int c = lofs[t];
    const int base = atomicAdd(&bucket_next[t], c);
    lofs[t] = t * BCAP + base;
  }
  __syncthreads();

  for (int e = e0 + t; e < e1; e += 1024) {
    const int d = dst[e];
    const int s = src[e];
    const float2 as = attn_s[s];
    const float2 ad = attn_d[d];
    float l0 = as.x + ad.x;
    float l1 = as.y + ad.y;
    l0 = (l0 > 0.0f) ? l0 : NEG * l0;
    l1 = (l1 > 0.0f) ? l1 : NEG * l1;
    const uint32_t wp = cvt1(__expf(l0)) | (cvt1(__expf(l1)) << 16);
    const int pos = atomicAdd(&lofs[d >> 11], 1);
    tmp[pos] = ((unsigned long long)(unsigned)s << 43)
             | ((unsigned long long)(unsigned)(d & 2047) << 32)
             | (unsigned long long)wp;
  }
}

// ---------------------------------------------------------------------------
// rs build: one block per bucket. LDS-histogram the 11-bit local dst over the
// bucket's records, block-scan, write rs/next coalesced.
// ---------------------------------------------------------------------------
__global__ __launch_bounds__(1024) void rs_build_kernel(
    const unsigned long long* __restrict__ tmp,
    const int* __restrict__ bucket_next,
    int* __restrict__ rs, int* __restrict__ next)
{
  __shared__ int hist[2048];
  __shared__ int ps[1024];
  __shared__ int bstart_s;
  const int b = blockIdx.x;
  const int t = threadIdx.x;
  hist[t] = 0;
  hist[t + 1024] = 0;
  if (t == 0) {
    int ssum = 0;
    for (int k = 0; k < b; ++k) ssum += bucket_next[k];
    bstart_s = ssum;
  }
  __syncthreads();

  const int ncnt = bucket_next[b];
  const unsigned long long* base = tmp + (size_t)b * BCAP;
  for (int i = t; i < ncnt; i += 1024)
    atomicAdd(&hist[(int)((base[i] >> 32) & 2047)], 1);
  __syncthreads();

  const int h0 = hist[2 * t];
  const int h1 = hist[2 * t + 1];
  const int pv = h0 + h1;
  ps[t] = pv;
  __syncthreads();
  int x = pv;
  for (int o = 1; o < 1024; o <<= 1) {
    const int y = (t >= o) ? ps[t - o] : 0;
    __syncthreads();
    x += y;
    ps[t] = x;
    __syncthreads();
  }
  const int e0 = bstart_s + x - pv;          // exclusive prefix at node 2t
  const int n0 = b * 2048 + 2 * t;
  if (n0 < NN)     { rs[n0] = e0;          next[n0] = e0; }
  if (n0 + 1 < NN) { rs[n0 + 1] = e0 + h0; next[n0 + 1] = e0 + h0; }
  if (b == NBUCK - 1 && t == 0) rs[NN] = NE;
}

// ---------------------------------------------------------------------------
// Pass 2: bucket -> final CSR. All 8 sub-blocks of a bucket share
// blockIdx%8 (same XCD under round-robin dispatch); the bucket's ~256 KB
// CSR region stays in one L2, lines flush once, full.
// ---------------------------------------------------------------------------
__global__ __launch_bounds__(256) void csr_kernel(
    const unsigned long long* __restrict__ tmp,
    const int* __restrict__ bucket_next,
    int* __restrict__ next, uint2* __restrict__ edges)
{
  const int p  = blockIdx.x & 7;
  const int tq = blockIdx.x >> 3;        // 0..55
  const int bq = tq >> 3;                // 0..6
  const int j  = tq & 7;                 // sub-block 0..7
  const int b  = p + 8 * bq;
  if (b >= NBUCK) return;
  const int ncnt = bucket_next[b];
  const int chunk = (ncnt + 7) >> 3;
  const int i0 = j * chunk;
  const int i1 = min(i0 + chunk, ncnt);
  const unsigned long long* base = tmp + (size_t)b * BCAP;
  for (int i = i0 + threadIdx.x; i < i1; i += 256) {
    const unsigned long long r = base[i];
    const int s = (int)(r >> 43);
    const int d = (b << 11) + (int)((r >> 32) & 2047);
    const uint32_t wp = (uint32_t)r;
    const int pos = atomicAdd(&next[d], 1);
    edges[pos] = make_uint2((unsigned)s * 256u, wp);
  }
}

// ---------------------------------------------------------------------------
// Aggregation: one wave per destination node; 8 B records (bf16 weights);
// 3-stage, 8-edge-wide pipeline.
// ---------------------------------------------------------------------------
__global__ __launch_bounds__(256) void aggregate_kernel(
    const int* __restrict__ rs, const uint2* __restrict__ edges,
    const ushort* __restrict__ src_fc, float* __restrict__ out)
{
  int wid = (int)((blockIdx.x * (size_t)blockDim.x + threadIdx.x) >> 6);
  if (wid >= NN) return;
  wid = __builtin_amdgcn_readfirstlane(wid);
  const int lane = threadIdx.x & 63;
  const int start = rs[wid];
  const int end = rs[wid + 1];
  const int deg = end - start;
  if (deg == 0) return;   // isolated node: out already = feat_dst_fc

  const bool h0 = (lane < 32);
  const unsigned lane4 = lane * 4;          // byte offset within bf16 row
  const char* fcb = (const char*)src_fc;
  const int nb = (deg + 7) >> 3;

  struct Batch { uint2 e[8]; };
  struct Rows  { uint32_t r[8]; };

  auto loadE = [&](int b, Batch& B) {
    const int base = start + b * 8;
#pragma unroll
    for (int j = 0; j < 8; ++j) {
      const int idx = (base + j < end) ? base + j : start;
      B.e[j] = edges[idx];                   // uniform -> scalar loads
    }
  };
  auto loadR = [&](const Batch& B, Rows& R) {
#pragma unroll
    for (int j = 0; j < 8; ++j)
      R.r[j] = *(const uint32_t*)(fcb + (B.e[j].x + lane4));
  };

  float acc0 = 0.0f, acc1 = 0.0f, dh = 0.0f;
  auto compute = [&](int b, const Batch& B, const Rows& R) {
    const int rem = deg - b * 8;
#pragma unroll
    for (int j = 0; j < 8; ++j) {
      const uint32_t wp = (j < rem) ? B.e[j].y : 0u;   // scalar select
      const float w0 = __uint_as_float(wp << 16);
      const float w1 = __uint_as_float(wp & 0xffff0000u);
      const float wh = h0 ? w0 : w1;
      dh += wh;
      acc0 = fmaf(__uint_as_float(R.r[j] << 16), wh, acc0);
      acc1 = fmaf(__uint_as_float(R.r[j] & 0xffff0000u), wh, acc1);
    }
  };

  Batch bA, bB;
  Rows rA;
  loadE(0, bA);
  loadR(bA, rA);
  if (nb > 1) loadE(1, bB); else bB = bA;

  for (int b = 0; b < nb; ++b) {
    Rows rB = rA;
    if (b + 1 < nb) loadR(bB, rB);
    Batch bC = bB;
    if (b + 2 < nb) loadE(b + 2, bC);
    compute(b, bA, rA);
    bA = bB; rA = rB; bB = bC;
  }

  const float inv = 1.0f / dh;
  float2* po = (float2*)(out + (size_t)wid * 128 + 2 * lane);
  float2 cur = *po;
  cur.x = fmaf(acc0, inv, cur.x);
  cur.y = fmaf(acc1, inv, cur.y);
  *po = cur;
}

// ---------------------------------------------------------------------------
extern "C" void kernel_launch(void* const* d_in, const int* in_sizes, int n_in,
                              void* d_out, int out_size, void* d_ws, size_t ws_size,
                              hipStream_t stream)
{
  const float* feat    = (const float*)d_in[0];
  const int*   src_idx = (const int*)d_in[1];
  const int*   dst_idx = (const int*)d_in[2];
  const float* Wsrc    = (const float*)d_in[3];
  const float* Wdst    = (const float*)d_in[4];
  const float* bdst    = (const float*)d_in[5];
  const float* asrc    = (const float*)d_in[6];
  const float* adst    = (const float*)d_in[7];
  float* out = (float*)d_out;

  char* ws = (char*)d_ws;
  size_t off = 0;
  auto alloc = [&](size_t bytes) -> void* {
    void* p = ws + off;
    off = (off + bytes + 255) & ~(size_t)255;
    return p;
  };
  ushort* src_fc  = (ushort*)alloc((size_t)NN * 128 * sizeof(ushort));   // 25.6 MB
  float*  attn_s  = (float*)alloc((size_t)NN * 2 * sizeof(float));
  float*  attn_d  = (float*)alloc((size_t)NN * 2 * sizeof(float));
  int*    rs      = (int*)alloc((size_t)(NN + 1) * sizeof(int));
  int*    next    = (int*)alloc((size_t)NN * sizeof(int));
  uint2*  edges   = (uint2*)alloc((size_t)NE * sizeof(uint2));           // 12.8 MB
  unsigned long long* tmp =
      (unsigned long long*)alloc((size_t)NBUCK * BCAP * sizeof(unsigned long long)); // 14.5 MB
  int*    bnext   = (int*)alloc((size_t)NBUCK * sizeof(int));
  ushort* wb      = (ushort*)alloc((size_t)256 * 128 * sizeof(ushort));

  hipMemsetAsync(bnext, 0, (size_t)NBUCK * sizeof(int), stream);

  cvt_w_kernel<<<16, 256, 0, stream>>>(Wsrc, Wdst, wb);
  gemm_kernel<<<1563, 256, 0, stream>>>(feat, wb, bdst, src_fc, out);
  attn_kernel<<<1024, 256, 0, stream>>>(feat, asrc, adst,
                                        (float2*)attn_s, (float2*)attn_d);
  bucket_kernel<<<NBLK1, 1024, 0, stream>>>(
      src_idx, dst_idx, (const float2*)attn_s, (const float2*)attn_d,
      bnext, tmp);
  rs_build_kernel<<<NBUCK, 1024, 0, stream>>>(tmp, bnext, rs, next);
  csr_kernel<<<448, 256, 0, stream>>>(tmp, bnext, next, edges);
  aggregate_kernel<<<(NN * 64) / 256, 256, 0, stream>>>(rs, edges, src_fc, out);
}

// Round 10
// 190.625 us; speedup vs baseline: 1.6550x; 1.1736x over previous
//
#include <hip/hip_runtime.h>
#include <cstdint>
#include <cstddef>

static constexpr int NN = 100000;
static constexpr int NE = 1600000;
static constexpr float NEG = 0.2f;
static constexpr int NBUCK = 49;                 // dst >> 11 (2048 nodes/bucket)
static constexpr int BCAP  = 36864;              // mean 32768 + ~22 sigma slack
static constexpr int NBLK1 = 512;
static constexpr int CHUNK1 = (NE + NBLK1 - 1) / NBLK1;  // 3125

typedef __attribute__((ext_vector_type(8))) short short8v;   // 8 bf16 (4 VGPRs)
typedef __attribute__((ext_vector_type(4))) float floatx4;   // 4 f32 acc

// ---------------------------------------------------------------------------
__device__ inline short8v cvt8(const float4 a, const float4 b)
{
  const float v[8] = {a.x, a.y, a.z, a.w, b.x, b.y, b.z, b.w};
  uint32_t q[8];
#pragma unroll
  for (int j = 0; j < 8; ++j) {
    uint32_t u = __float_as_uint(v[j]);
    u += 0x7fff + ((u >> 16) & 1);   // round-to-nearest-even
    q[j] = u >> 16;
  }
  union { uint32_t u[4]; short8v s; } r;
  r.u[0] = q[0] | (q[1] << 16);
  r.u[1] = q[2] | (q[3] << 16);
  r.u[2] = q[4] | (q[5] << 16);
  r.u[3] = q[6] | (q[7] << 16);
  return r.s;
}

__device__ inline uint32_t cvt1(float x)
{
  uint32_t u = __float_as_uint(x);
  u += 0x7fff + ((u >> 16) & 1);
  return u >> 16;
}

// ---------------------------------------------------------------------------
// Build wb[272][128] bf16: rows 0-127 Wsrc, 128-255 Wdst, 256-257 a_src,
// 258-259 a_dst, 260-271 zero pad (so attn becomes 4 extra GEMM columns).
// ---------------------------------------------------------------------------
__global__ __launch_bounds__(256) void cvt_w_kernel(
    const float* __restrict__ Wsrc, const float* __restrict__ Wdst,
    const float* __restrict__ asrc, const float* __restrict__ adst,
    ushort* __restrict__ wb)
{
  const int i = (blockIdx.x * 256 + threadIdx.x) * 8;
  if (i >= 34816) return;
  const float* src;
  if (i < 16384)      src = Wsrc + i;
  else if (i < 32768) src = Wdst + (i - 16384);
  else if (i < 33024) src = asrc + (i - 32768);
  else if (i < 33280) src = adst + (i - 33024);
  else { *(short8v*)(wb + i) = short8v{0,0,0,0,0,0,0,0}; return; }
  float4 a = *(const float4*)(src);
  float4 b = *(const float4*)(src + 4);
  *(short8v*)(wb + i) = cvt8(a, b);
}

// ---------------------------------------------------------------------------
// MFMA projection GEMM with LDS-staged A (loaded once per block) and FUSED
// attention projections: wave 3 computes the 272-col tile (cols 256-271,
// first 4 = attn logits) with 4 extra MFMAs and scatters them to attn_s/d.
// Cols 0-127 -> src_fc (bf16), 128-255 -> out (f32 + bias).
// ---------------------------------------------------------------------------
__global__ __launch_bounds__(256) void gemm_kernel(
    const float* __restrict__ feat, const ushort* __restrict__ wb,
    const float* __restrict__ bdst,
    ushort* __restrict__ src_fc, float* __restrict__ out,
    float* __restrict__ attn_s, float* __restrict__ attn_d)
{
  __shared__ __align__(16) ushort atile[2048];   // 16 x 128 bf16, swizzled

  const int t    = threadIdx.x;
  const int lane = t & 63;
  const int w    = t >> 6;                 // wave 0..3
  const int c0   = w * 64;
  const int colq = lane & 15;
  const int kgrp = lane >> 4;

  short8v bf[4][4];
#pragma unroll
  for (int nt = 0; nt < 4; ++nt)
#pragma unroll
    for (int kt = 0; kt < 4; ++kt)
      bf[nt][kt] = *(const short8v*)(wb + (size_t)(c0 + nt * 16 + colq) * 128
                                        + kt * 32 + kgrp * 8);
  short8v bfa[4];
  if (w == 3) {
#pragma unroll
    for (int kt = 0; kt < 4; ++kt)
      bfa[kt] = *(const short8v*)(wb + (size_t)(256 + colq) * 128
                                     + kt * 32 + kgrp * 8);
  }

  float bias[4];
#pragma unroll
  for (int nt = 0; nt < 4; ++nt) {
    const int col = c0 + nt * 16 + colq;
    bias[nt] = (col >= 128) ? bdst[col - 128] : 0.0f;
  }
  const bool is_dst = (c0 >= 128);

  const int sr = t >> 4;                   // staging row 0..15
  const int sc = t & 15;                   // staging col-group (8 floats)
  const unsigned sw_off = (unsigned)((sr * 256 + sc * 16) ^ ((sr & 7) << 4));
  unsigned rd_off[4];
#pragma unroll
  for (int kt = 0; kt < 4; ++kt)
    rd_off[kt] = (unsigned)((colq * 256 + kt * 64 + kgrp * 16) ^ ((colq & 7) << 4));

  for (int mt = blockIdx.x; mt < NN / 16; mt += gridDim.x) {
    const int row0 = mt * 16;
    {
      const float* ap = feat + (size_t)(row0 + sr) * 128 + sc * 8;
      float4 a = *(const float4*)ap;
      float4 b = *(const float4*)(ap + 4);
      *(short8v*)((char*)atile + sw_off) = cvt8(a, b);
    }
    __syncthreads();
    short8v af[4];
#pragma unroll
    for (int kt = 0; kt < 4; ++kt)
      af[kt] = *(const short8v*)((const char*)atile + rd_off[kt]);
    __syncthreads();   // reads drained before next iter's writes

    floatx4 acc[4] = {{0,0,0,0},{0,0,0,0},{0,0,0,0},{0,0,0,0}};
#pragma unroll
    for (int kt = 0; kt < 4; ++kt)
#pragma unroll
      for (int nt = 0; nt < 4; ++nt)
        acc[nt] = __builtin_amdgcn_mfma_f32_16x16x32_bf16(af[kt], bf[nt][kt],
                                                          acc[nt], 0, 0, 0);
    // C/D: col = lane&15, row = (lane>>4)*4 + reg
#pragma unroll
    for (int nt = 0; nt < 4; ++nt) {
      const int col = c0 + nt * 16 + colq;
#pragma unroll
      for (int j = 0; j < 4; ++j) {
        const int rr = row0 + kgrp * 4 + j;
        if (!is_dst) src_fc[(size_t)rr * 128 + col] = (ushort)cvt1(acc[nt][j]);
        else         out[(size_t)rr * 128 + (col - 128)] = acc[nt][j] + bias[nt];
      }
    }
    if (w == 3) {                          // fused attention columns
      floatx4 acca = {0, 0, 0, 0};
#pragma unroll
      for (int kt = 0; kt < 4; ++kt)
        acca = __builtin_amdgcn_mfma_f32_16x16x32_bf16(af[kt], bfa[kt],
                                                       acca, 0, 0, 0);
      if (colq < 4) {
        float* dstp = (colq < 2) ? attn_s : attn_d;
        const int c2 = colq & 1;
#pragma unroll
        for (int j = 0; j < 4; ++j) {
          const int rr = row0 + kgrp * 4 + j;
          dstp[2 * rr + c2] = acca[j];
        }
      }
    }
  }
}

// ---------------------------------------------------------------------------
// Pass 1: coarse-bucket append. Record (u64):
// [src:17 | dloc:11 | w0bf16:16 | w1bf16:16]. Two-pass per block: LDS bucket
// count -> one global reservation per bucket -> dense append.
// ---------------------------------------------------------------------------
__global__ __launch_bounds__(1024) void bucket_kernel(
    const int* __restrict__ src, const int* __restrict__ dst,
    const float2* __restrict__ attn_s, const float2* __restrict__ attn_d,
    int* __restrict__ bucket_next, unsigned long long* __restrict__ tmp)
{
  __shared__ int lofs[NBUCK];
  const int t = threadIdx.x;
  if (t < NBUCK) lofs[t] = 0;
  __syncthreads();

  const int e0 = blockIdx.x * CHUNK1;
  const int e1 = min(e0 + CHUNK1, NE);
  for (int e = e0 + t; e < e1; e += 1024)
    atomicAdd(&lofs[dst[e] >> 11], 1);
  __syncthreads();

  if (t < NBUCK) {
    const int c = lofs[t];
    const int base = atomicAdd(&bucket_next[t], c);
    lofs[t] = t * BCAP + base;
  }
  __syncthreads();

  for (int e = e0 + t; e < e1; e += 1024) {
    const int d = dst[e];
    const int s = src[e];
    const float2 as = attn_s[s];
    const float2 ad = attn_d[d];
    float l0 = as.x + ad.x;
    float l1 = as.y + ad.y;
    l0 = (l0 > 0.0f) ? l0 : NEG * l0;
    l1 = (l1 > 0.0f) ? l1 : NEG * l1;
    const uint32_t wp = cvt1(__expf(l0)) | (cvt1(__expf(l1)) << 16);
    const int pos = atomicAdd(&lofs[d >> 11], 1);
    tmp[pos] = ((unsigned long long)(unsigned)s << 43)
             | ((unsigned long long)(unsigned)(d & 2047) << 32)
             | (unsigned long long)wp;
  }
}

// ---------------------------------------------------------------------------
// Fused rs-build + CSR scatter: one block per bucket. LDS histogram of the
// 11-bit local dst -> block scan -> write rs (coalesced) -> scatter the
// bucket's records to final CSR slots using the scanned LDS offsets as
// running counters (no global `next` array, no cross-XCD atomics; the
// bucket's ~260 KB CSR region stays in this XCD's L2).
// ---------------------------------------------------------------------------
__global__ __launch_bounds__(1024) void rs_csr_kernel(
    const unsigned long long* __restrict__ tmp,
    const int* __restrict__ bucket_next,
    int* __restrict__ rs, uint2* __restrict__ edges)
{
  __shared__ int hist[2048];
  __shared__ int ps[1024];
  __shared__ int bstart_s;
  const int b = blockIdx.x;
  const int t = threadIdx.x;
  hist[t] = 0;
  hist[t + 1024] = 0;
  if (t == 0) {
    int ssum = 0;
    for (int k = 0; k < b; ++k) ssum += bucket_next[k];
    bstart_s = ssum;
  }
  __syncthreads();

  const int ncnt = bucket_next[b];
  const unsigned long long* base = tmp + (size_t)b * BCAP;
  for (int i = t; i < ncnt; i += 1024)
    atomicAdd(&hist[(int)((base[i] >> 32) & 2047)], 1);
  __syncthreads();

  const int h0 = hist[2 * t];
  const int h1 = hist[2 * t + 1];
  const int pv = h0 + h1;
  ps[t] = pv;
  __syncthreads();
  int x = pv;
  for (int o = 1; o < 1024; o <<= 1) {
    const int y = (t >= o) ? ps[t - o] : 0;
    __syncthreads();
    x += y;
    ps[t] = x;
    __syncthreads();
  }
  const int e0 = bstart_s + x - pv;          // exclusive prefix at node 2t
  hist[2 * t]     = e0;                      // becomes running write cursor
  hist[2 * t + 1] = e0 + h0;
  const int n0 = b * 2048 + 2 * t;
  if (n0 < NN)     rs[n0] = e0;
  if (n0 + 1 < NN) rs[n0 + 1] = e0 + h0;
  if (b == NBUCK - 1 && t == 0) rs[NN] = NE;
  __syncthreads();

  for (int i = t; i < ncnt; i += 1024) {
    const unsigned long long r = base[i];
    const int s = (int)(r >> 43);
    const int dloc = (int)((r >> 32) & 2047);
    const int pos = atomicAdd(&hist[dloc], 1);
    edges[pos] = make_uint2((unsigned)s * 256u, (uint32_t)r);
  }
}

// ---------------------------------------------------------------------------
// Aggregation: one wave per destination node; 8 B records (bf16 weights);
// 3-stage, 8-edge-wide pipeline.
// ---------------------------------------------------------------------------
__global__ __launch_bounds__(256) void aggregate_kernel(
    const int* __restrict__ rs, const uint2* __restrict__ edges,
    const ushort* __restrict__ src_fc, float* __restrict__ out)
{
  int wid = (int)((blockIdx.x * (size_t)blockDim.x + threadIdx.x) >> 6);
  if (wid >= NN) return;
  wid = __builtin_amdgcn_readfirstlane(wid);
  const int lane = threadIdx.x & 63;
  const int start = rs[wid];
  const int end = rs[wid + 1];
  const int deg = end - start;
  if (deg == 0) return;   // isolated node: out already = feat_dst_fc

  const bool h0 = (lane < 32);
  const unsigned lane4 = lane * 4;          // byte offset within bf16 row
  const char* fcb = (const char*)src_fc;
  const int nb = (deg + 7) >> 3;

  struct Batch { uint2 e[8]; };
  struct Rows  { uint32_t r[8]; };

  auto loadE = [&](int b, Batch& B) {
    const int base = start + b * 8;
#pragma unroll
    for (int j = 0; j < 8; ++j) {
      const int idx = (base + j < end) ? base + j : start;
      B.e[j] = edges[idx];                   // uniform -> scalar loads
    }
  };
  auto loadR = [&](const Batch& B, Rows& R) {
#pragma unroll
    for (int j = 0; j < 8; ++j)
      R.r[j] = *(const uint32_t*)(fcb + (B.e[j].x + lane4));
  };

  float acc0 = 0.0f, acc1 = 0.0f, dh = 0.0f;
  auto compute = [&](int b, const Batch& B, const Rows& R) {
    const int rem = deg - b * 8;
#pragma unroll
    for (int j = 0; j < 8; ++j) {
      const uint32_t wp = (j < rem) ? B.e[j].y : 0u;   // scalar select
      const float w0 = __uint_as_float(wp << 16);
      const float w1 = __uint_as_float(wp & 0xffff0000u);
      const float wh = h0 ? w0 : w1;
      dh += wh;
      acc0 = fmaf(__uint_as_float(R.r[j] << 16), wh, acc0);
      acc1 = fmaf(__uint_as_float(R.r[j] & 0xffff0000u), wh, acc1);
    }
  };

  Batch bA, bB;
  Rows rA;
  loadE(0, bA);
  loadR(bA, rA);
  if (nb > 1) loadE(1, bB); else bB = bA;

  for (int b = 0; b < nb; ++b) {
    Rows rB = rA;
    if (b + 1 < nb) loadR(bB, rB);
    Batch bC = bB;
    if (b + 2 < nb) loadE(b + 2, bC);
    compute(b, bA, rA);
    bA = bB; rA = rB; bB = bC;
  }

  const float inv = 1.0f / dh;
  float2* po = (float2*)(out + (size_t)wid * 128 + 2 * lane);
  float2 cur = *po;
  cur.x = fmaf(acc0, inv, cur.x);
  cur.y = fmaf(acc1, inv, cur.y);
  *po = cur;
}

// ---------------------------------------------------------------------------
extern "C" void kernel_launch(void* const* d_in, const int* in_sizes, int n_in,
                              void* d_out, int out_size, void* d_ws, size_t ws_size,
                              hipStream_t stream)
{
  const float* feat    = (const float*)d_in[0];
  const int*   src_idx = (const int*)d_in[1];
  const int*   dst_idx = (const int*)d_in[2];
  const float* Wsrc    = (const float*)d_in[3];
  const float* Wdst    = (const float*)d_in[4];
  const float* bdst    = (const float*)d_in[5];
  const float* asrc    = (const float*)d_in[6];
  const float* adst    = (const float*)d_in[7];
  float* out = (float*)d_out;

  char* ws = (char*)d_ws;
  size_t off = 0;
  auto alloc = [&](size_t bytes) -> void* {
    void* p = ws + off;
    off = (off + bytes + 255) & ~(size_t)255;
    return p;
  };
  ushort* src_fc  = (ushort*)alloc((size_t)NN * 128 * sizeof(ushort));   // 25.6 MB
  float*  attn_s  = (float*)alloc((size_t)NN * 2 * sizeof(float));
  float*  attn_d  = (float*)alloc((size_t)NN * 2 * sizeof(float));
  int*    rs      = (int*)alloc((size_t)(NN + 1) * sizeof(int));
  uint2*  edges   = (uint2*)alloc((size_t)NE * sizeof(uint2));           // 12.8 MB
  unsigned long long* tmp =
      (unsigned long long*)alloc((size_t)NBUCK * BCAP * sizeof(unsigned long long)); // 14.5 MB
  int*    bnext   = (int*)alloc((size_t)NBUCK * sizeof(int));
  ushort* wb      = (ushort*)alloc((size_t)272 * 128 * sizeof(ushort));

  hipMemsetAsync(bnext, 0, (size_t)NBUCK * sizeof(int), stream);

  cvt_w_kernel<<<17, 256, 0, stream>>>(Wsrc, Wdst, asrc, adst, wb);
  gemm_kernel<<<1563, 256, 0, stream>>>(feat, wb, bdst, src_fc, out,
                                        attn_s, attn_d);
  bucket_kernel<<<NBLK1, 1024, 0, stream>>>(
      src_idx, dst_idx, (const float2*)attn_s, (const float2*)attn_d,
      bnext, tmp);
  rs_csr_kernel<<<NBUCK, 1024, 0, stream>>>(tmp, bnext, rs, edges);
  aggregate_kernel<<<(NN * 64) / 256, 256, 0, stream>>>(rs, edges, src_fc, out);
}